// Round 2
// baseline (276.668 us; speedup 1.0000x reference)
//
#include <hip/hip_runtime.h>
#include <stdint.h>

// ---- types ----
typedef unsigned short u16;
typedef __attribute__((ext_vector_type(4))) float f32x4;
typedef __attribute__((ext_vector_type(8))) __bf16 bf16x8;
typedef __attribute__((ext_vector_type(4))) unsigned int u32x4;

#define HWPX 4096   // H*W pixels
#define NMEM 8192   // T*H*W memory slots
#define CKD  64
#define VROWS 1024  // NOBJ*CV

__device__ __forceinline__ u16 f2bf(float x) {
    union { float f; unsigned u; } v; v.f = x;
    unsigned r = v.u + 0x7FFFu + ((v.u >> 16) & 1u);
    return (u16)(r >> 16);
}

// async global->LDS, 16B per lane; lds base wave-uniform (HW adds lane*16)
__device__ __forceinline__ void gld_lds16(const void* g, void* l) {
    __builtin_amdgcn_global_load_lds(
        (const __attribute__((address_space(1))) uint32_t*)g,
        (__attribute__((address_space(3))) uint32_t*)l, 16, 0, 0);
}

// -------- k1: tiny prep for gemm1's inputs only: Qhat/bsq (16) | Khat (32) ----
__global__ void prep_qk(const float* __restrict__ qk, const float* __restrict__ qe,
                        const float* __restrict__ mk,
                        u16* __restrict__ Qhat, float* __restrict__ bsq,
                        u16* __restrict__ Khat) {
    const int bx = blockIdx.x;
    const int tid = threadIdx.x;
    if (bx < 16) {
        int p = bx * 256 + tid;   // 4096
        float acc = 0.f;
        #pragma unroll 4
        for (int c = 0; c < CKD; ++c) {
            float k = qk[c * HWPX + p];
            float e = qe[c * HWPX + p];
            Qhat[p * 128 + c]      = f2bf(k * e);
            Qhat[p * 128 + 64 + c] = f2bf(e);
            acc += e * k * k;
        }
        bsq[p] = acc;
    } else {
        int n = (bx - 16) * 256 + tid;   // 8192
        #pragma unroll 4
        for (int c = 0; c < CKD; ++c) {
            float m = mk[c * NMEM + n];
            Khat[n * 128 + c]      = f2bf(2.f * m);
            Khat[n * 128 + 64 + c] = f2bf(-m * m);
        }
    }
}

// ---- k2: gemm1 tiles (4096 blocks of 64p x 128n) + mv->bf16 (512) + out zero (256)
// (unchanged; passes checker)
__launch_bounds__(256, 6)
__global__ void gemm1_combo(const u16* __restrict__ Qhat, const u16* __restrict__ Khat,
                            const float* __restrict__ bsq, const float* __restrict__ ms,
                            const float* __restrict__ mv,
                            u16* __restrict__ Pt, float* __restrict__ dpart,
                            u16* __restrict__ mvb, float* __restrict__ outz) {
    const int blk = blockIdx.x;
    const int tid = threadIdx.x;

    if (blk < 512) {               // mv -> bf16 (2M float4s, 4096 per block)
        #pragma unroll 4
        for (int it = 0; it < 16; ++it) {
            int i = blk * 4096 + it * 256 + tid;
            float4 v = ((const float4*)mv)[i];
            u16 o0 = f2bf(v.x), o1 = f2bf(v.y), o2 = f2bf(v.z), o3 = f2bf(v.w);
            unsigned lo = (unsigned)o0 | ((unsigned)o1 << 16);
            unsigned hi = (unsigned)o2 | ((unsigned)o3 << 16);
            ((uint2*)mvb)[i] = make_uint2(lo, hi);
        }
        return;
    }
    if (blk < 768) {               // zero out (1M float4s, 4096 per block)
        #pragma unroll 4
        for (int it = 0; it < 16; ++it) {
            int i = (blk - 512) * 4096 + it * 256 + tid;
            ((float4*)outz)[i] = make_float4(0.f, 0.f, 0.f, 0.f);
        }
        return;
    }

    // ---------------- gemm1 tile: 64 p-rows x 128 n-cols ----------------
    __shared__ __align__(16) u16 smem[12288];   // 24 KB
    u16* Qs = smem;                 // [64][64] per pass
    u16* Ks = smem + 4096;          // [128][64] per pass

    const int tile = blk - 768;     // 0..4095
    const int bx = tile & 63;       // p-tile (64 wide)
    const int by = tile >> 6;       // n-tile (128 wide), 0..63
    const int p0 = bx * 64;
    const int n0 = by * 128;

    const int l    = tid & 63;
    const int w    = tid >> 6;
    const int quad = l >> 4;
    const int l15  = l & 15;
    const int wm = w >> 1, wn = w & 1;   // wave tile: 32p x 64n

    const int rsub = tid >> 3;                      // 0..31 (row within round)
    const int csw  = (tid & 7) ^ (rsub & 7);        // swizzled source chunk

    f32x4 acc[2][4] = {};

    #pragma unroll
    for (int h = 0; h < 2; ++h) {
        if (h) __syncthreads();     // protect stage region from pass-0 readers
        #pragma unroll
        for (int rnd = 0; rnd < 2; ++rnd)   // Q: 64 rows
            gld_lds16(Qhat + (size_t)(p0 + rnd * 32 + rsub) * 128 + h * 64 + csw * 8,
                      Qs + rnd * 2048 + w * 512);
        #pragma unroll
        for (int rnd = 0; rnd < 4; ++rnd)   // K: 128 rows
            gld_lds16(Khat + (size_t)(n0 + rnd * 32 + rsub) * 128 + h * 64 + csw * 8,
                      Ks + rnd * 2048 + w * 512);
        __syncthreads();
        #pragma unroll
        for (int kk = 0; kk < 2; ++kk) {
            bf16x8 a[2], b[4];
            #pragma unroll
            for (int mi = 0; mi < 2; ++mi) {
                int row = wm * 32 + mi * 16 + l15;
                a[mi] = *(const bf16x8*)(Qs + row * 64 + (((kk * 4 + quad) ^ (l15 & 7)) << 3));
            }
            #pragma unroll
            for (int ni = 0; ni < 4; ++ni) {
                int row = wn * 64 + ni * 16 + l15;
                b[ni] = *(const bf16x8*)(Ks + row * 64 + (((kk * 4 + quad) ^ (l15 & 7)) << 3));
            }
            #pragma unroll
            for (int mi = 0; mi < 2; ++mi)
                #pragma unroll
                for (int ni = 0; ni < 4; ++ni)
                    acc[mi][ni] = __builtin_amdgcn_mfma_f32_16x16x32_bf16(a[mi], b[ni], acc[mi][ni], 0, 0, 0);
        }
    }

    // per-lane epilogue constants
    float msv[4];
    #pragma unroll
    for (int ni = 0; ni < 4; ++ni)
        msv[ni] = ms[n0 + wn * 64 + ni * 16 + l15] * 0.125f;
    float bsv[2][4];
    #pragma unroll
    for (int mi = 0; mi < 2; ++mi)
        #pragma unroll
        for (int r = 0; r < 4; ++r)
            bsv[mi][r] = bsq[p0 + wm * 32 + mi * 16 + quad * 4 + r];

    __syncthreads();             // all waves done with stage region
    u16* Ps = smem;              // [64][136] padded u16 (17 KB)
    float rowsum[2][4] = {};
    #pragma unroll
    for (int mi = 0; mi < 2; ++mi) {
        #pragma unroll
        for (int ni = 0; ni < 4; ++ni) {
            f32x4 v = acc[mi][ni];
            int col = wn * 64 + ni * 16 + l15;
            #pragma unroll
            for (int r = 0; r < 4; ++r) {
                int rowl = wm * 32 + mi * 16 + quad * 4 + r;
                float pv = __expf((v[r] - bsv[mi][r]) * msv[ni]);
                rowsum[mi][r] += pv;
                Ps[rowl * 136 + col] = f2bf(pv);
            }
        }
    }
    // butterfly full-reduce over the 16-lane l15 group (8 sums/wave)
    #pragma unroll
    for (int mi = 0; mi < 2; ++mi)
        #pragma unroll
        for (int r = 0; r < 4; ++r) {
            float s = rowsum[mi][r];
            s += __shfl_xor(s, 1);
            s += __shfl_xor(s, 2);
            s += __shfl_xor(s, 4);
            s += __shfl_xor(s, 8);
            rowsum[mi][r] = s;
        }
    // exclusive-slot store: lane l15<8 owns (mi,r) = (l15>>2, l15&3); no atomics
    if (l15 < 8) {
        float myv = 0.f;
        #pragma unroll
        for (int mi = 0; mi < 2; ++mi)
            #pragma unroll
            for (int r = 0; r < 4; ++r)
                if (l15 == mi * 4 + r) myv = rowsum[mi][r];
        int slice = by * 2 + wn;   // 0..127 (64-n spans)
        dpart[(size_t)slice * HWPX + p0 + wm * 32 + (l15 >> 2) * 16 + quad * 4 + (l15 & 3)] = myv;
    }
    __syncthreads();

    // tiled Pt store: this block owns a contiguous 16 KB half of tile [pb][by]
    {
        const int pb = bx >> 1;
        const size_t dstBase = ((size_t)pb * 64 + by) * 16384 + (size_t)(bx & 1) * 8192;
        #pragma unroll
        for (int i = 0; i < 4; ++i) {
            int row = i * 16 + (tid >> 4);
            const u32x4* src = (const u32x4*)(Ps + row * 136 + (tid & 15) * 8);
            u32x4* dst = (u32x4*)(Pt + dstBase + i * 2048 + tid * 8);
            *dst = *src;
        }
    }
}

// ---------------- GEMM2 v3: A-direct-to-registers, B-only LDS ring ----------
// Diagnosis r1: both prior schedules pinned at 101.6us -> LDS read port under
// barrier-lockstep (0.03 LDS B/FLOP) was the wall, not barriers/TLP.
// Fix: A (mvb) frags load straight from global per-lane at MFMA frag layout
// (row=l&15, k=quad*8), reg-double-buffered one K-tile ahead; A is XCD-L2
// resident (lin&15 encodes (vb,kz): 2 panels = 2MB per XCD). Only B (Pt) goes
// through LDS (4x16KB ring, gld_lds, stage-ahead 2, counted vmcnt(4), ONE
// barrier per K-tile). 512 blocks x 256 thr = 2 independent blocks/CU (128KB
// LDS) -> de-lockstepped port. LDS reads/K-tile/CU: 128KB -> 64KB.
__launch_bounds__(256, 2)
__global__ void gemm2_kernel(const u16* __restrict__ Ab, const u16* __restrict__ Bt,
                             const float* __restrict__ dpart, float* __restrict__ outacc) {
    __shared__ __align__(16) u16 smem[4 * 8192];   // 64 KB: 4 B-buffers [128][64]

    const int tid  = threadIdx.x;
    const int l    = tid & 63;
    const int w    = tid >> 6;      // 0..3
    const int quad = l >> 4;
    const int l15  = l & 15;
    const int wm = w >> 1;          // 0..1 : v-offset wm*64
    const int wn = w & 1;           // 0..1 : p-offset wn*64

    const int lin  = blockIdx.x;    // 512 blocks
    const int vbkz = lin & 15;      // XCD = lin&7 -> 2 (vb,kz) A-panels per XCD
    const int pb   = lin >> 4;      // 0..31
    const int vb   = vbkz >> 1;     // 0..7
    const int kz   = vbkz & 1;
    const int v0 = vb * 128;
    const int p0 = pb * 128;
    const int kbeg = kz * (NMEM / 2);
    const int NT = (NMEM / 2) / 64; // 64 K-tiles

    const int rsub = tid >> 3;                 // 0..31 (row within stage round)
    const int csw  = (tid & 7) ^ (rsub & 7);   // swizzled source chunk

    // per-lane A row pointers: frag layout row = l&15, k = quad*8 (+ kk*32)
    const u16* aRow0 = Ab + (size_t)(v0 + wm * 64 +  0 + l15) * NMEM + quad * 8;
    const u16* aRow1 = Ab + (size_t)(v0 + wm * 64 + 16 + l15) * NMEM + quad * 8;
    const u16* aRow2 = Ab + (size_t)(v0 + wm * 64 + 32 + l15) * NMEM + quad * 8;
    const u16* aRow3 = Ab + (size_t)(v0 + wm * 64 + 48 + l15) * NMEM + quad * 8;

    // ds_read chunk offsets (both-sides XOR swizzle, row&7 == l15&7)
    const int c0 = ((0 + quad) ^ (l15 & 7)) << 3;
    const int c1 = ((4 + quad) ^ (l15 & 7)) << 3;
    const int bOff = (wn * 64 + l15) * 64;     // + ni*1024 + cK

    #define LOAD_A(dst, ko)                                                      \
        { dst[0][0] = *(const bf16x8*)(aRow0 + (ko));                            \
          dst[0][1] = *(const bf16x8*)(aRow0 + (ko) + 32);                       \
          dst[1][0] = *(const bf16x8*)(aRow1 + (ko));                            \
          dst[1][1] = *(const bf16x8*)(aRow1 + (ko) + 32);                       \
          dst[2][0] = *(const bf16x8*)(aRow2 + (ko));                            \
          dst[2][1] = *(const bf16x8*)(aRow2 + (ko) + 32);                       \
          dst[3][0] = *(const bf16x8*)(aRow3 + (ko));                            \
          dst[3][1] = *(const bf16x8*)(aRow3 + (ko) + 32); }

    #define STAGE_B(n0g, dst)                                                    \
        { const int nb_ = (n0g) >> 7, nh_ = ((n0g) >> 6) & 1;                    \
          const u16* bsrc_ = Bt + ((size_t)pb * 64 + nb_) * 16384 + nh_ * 64;    \
          _Pragma("unroll")                                                      \
          for (int rnd = 0; rnd < 4; ++rnd)                                      \
              gld_lds16(bsrc_ + (rnd * 32 + rsub) * 128 + csw * 8,               \
                        (dst) + rnd * 2048 + w * 512); }

    f32x4 acc[4][4] = {};
    bf16x8 aC[4][2], aN[4][2];

    // ---- prologue: A(0) to regs; B(0),B(1) to LDS ring; keep B(1) in flight
    LOAD_A(aC, kbeg)
    STAGE_B(kbeg, smem)
    STAGE_B(kbeg + 64, smem + 8192)
    asm volatile("s_waitcnt vmcnt(4)" ::: "memory");   // A(0)+B(0) done
    __builtin_amdgcn_s_barrier();
    __builtin_amdgcn_sched_barrier(0);

    // Per iter: read B-frags(t) | issue A(t+1)->regs | issue B(t+2)->ring |
    // 32 MFMA | vmcnt(4) (B(t+1)+A(t+1) done, B(t+2) stays in flight) | barrier
    #define BODY(T, AC, AN)                                                      \
    {   const int t_ = (T);                                                      \
        const u16* bufR = smem + ((t_ & 3) * 8192);                              \
        bf16x8 bfr[4][2];                                                        \
        _Pragma("unroll")                                                        \
        for (int ni = 0; ni < 4; ++ni) {                                         \
            bfr[ni][0] = *(const bf16x8*)(bufR + bOff + ni * 1024 + c0);         \
            bfr[ni][1] = *(const bf16x8*)(bufR + bOff + ni * 1024 + c1);         \
        }                                                                        \
        if (t_ + 1 < NT) LOAD_A(AN, kbeg + (t_ + 1) * 64)                        \
        if (t_ + 2 < NT) STAGE_B(kbeg + (t_ + 2) * 64, smem + (((t_ + 2) & 3) * 8192)) \
        __builtin_amdgcn_s_setprio(1);                                           \
        _Pragma("unroll")                                                        \
        for (int mi = 0; mi < 4; ++mi)                                           \
            _Pragma("unroll")                                                    \
            for (int ni = 0; ni < 4; ++ni) {                                     \
                acc[mi][ni] = __builtin_amdgcn_mfma_f32_16x16x32_bf16(AC[mi][0], bfr[ni][0], acc[mi][ni], 0, 0, 0); \
                acc[mi][ni] = __builtin_amdgcn_mfma_f32_16x16x32_bf16(AC[mi][1], bfr[ni][1], acc[mi][ni], 0, 0, 0); \
            }                                                                    \
        __builtin_amdgcn_s_setprio(0);                                           \
        if (t_ + 2 < NT) { asm volatile("s_waitcnt vmcnt(4)" ::: "memory"); }    \
        else             { asm volatile("s_waitcnt vmcnt(0)" ::: "memory"); }    \
        __builtin_amdgcn_s_barrier();                                            \
        __builtin_amdgcn_sched_barrier(0);                                       \
    }

    for (int tt = 0; tt < NT; tt += 2) {
        BODY(tt, aC, aN)
        BODY(tt + 1, aN, aC)
    }
    #undef BODY
    #undef STAGE_B
    #undef LOAD_A

    // ---- reconstruct 1/denom for this 128-p tile from the 128 dpart slices ----
    __syncthreads();                        // ring fully drained; LDS reusable
    float* dtmp  = (float*)smem;            // 256 partials (1 KB)
    float* dinvs = (float*)(smem + 2048);   // 128 inverses (at byte 4096)
    {
        int p = tid & 127, h = tid >> 7;    // h: slice half (64 slices each)
        float s = 0.f;
        #pragma unroll 8
        for (int sl = 0; sl < 64; ++sl)
            s += dpart[(size_t)(h * 64 + sl) * HWPX + p0 + p];
        dtmp[tid] = s;
    }
    __syncthreads();
    if (tid < 128) dinvs[tid] = 1.0f / (dtmp[tid] + dtmp[tid + 128]);
    __syncthreads();

    float dinv[4];
    #pragma unroll
    for (int ni = 0; ni < 4; ++ni)
        dinv[ni] = dinvs[wn * 64 + ni * 16 + l15];

    #pragma unroll
    for (int mi = 0; mi < 4; ++mi) {
        #pragma unroll
        for (int ni = 0; ni < 4; ++ni) {
            int col = p0 + wn * 64 + ni * 16 + l15;
            f32x4 v = acc[mi][ni];
            #pragma unroll
            for (int r = 0; r < 4; ++r) {
                int row = v0 + wm * 64 + mi * 16 + quad * 4 + r;
                atomicAdd(&outacc[(size_t)row * HWPX + col], v[r] * dinv[ni]);
            }
        }
    }
}

// ---------------- launch ----------------
extern "C" void kernel_launch(void* const* d_in, const int* in_sizes, int n_in,
                              void* d_out, int out_size, void* d_ws, size_t ws_size,
                              hipStream_t stream) {
    const float* qk = (const float*)d_in[0];  // (1,64,64,64)
    const float* qe = (const float*)d_in[1];  // (1,64,64,64)
    const float* mk = (const float*)d_in[2];  // (1,64,2,64,64)
    const float* ms = (const float*)d_in[3];  // (1,1,2,64,64)
    const float* mv = (const float*)d_in[4];  // (1,2,512,2,64,64)
    float* out = (float*)d_out;               // (1,2,512,64,64)

    char* ws = (char*)d_ws;
    u16*   Pt    = (u16*)ws;                               // 64 MB  tiled [32][64][128][128] bf16
    u16*   mvb   = (u16*)(ws + ((size_t)64 << 20));        // 16 MB  [1024][8192] bf16
    u16*   Khat  = (u16*)(ws + ((size_t)80 << 20));        // 2 MB   [8192][128]  bf16
    u16*   Qhat  = (u16*)(ws + ((size_t)82 << 20));        // 1 MB   [4096][128]  bf16
    float* bsq   = (float*)(ws + ((size_t)83 << 20));      // 16 KB
    float* dpart = (float*)(ws + ((size_t)83 << 20) + 65536); // 2 MB [128][4096] f32

    prep_qk<<<48, 256, 0, stream>>>(qk, qe, mk, Qhat, bsq, Khat);

    // 512 mv-convert + 256 out-zero + 4096 gemm1 tiles (64p x 128n)
    gemm1_combo<<<4864, 256, 0, stream>>>(Qhat, Khat, bsq, ms, mv, Pt, dpart, mvb, out);

    // 512 blocks = (vb x kz: lin&15) x (pb: lin>>4), 256 threads, 2 blocks/CU
    gemm2_kernel<<<512, 256, 0, stream>>>(mvb, Pt, dpart, out);
}

// Round 3
// 226.275 us; speedup vs baseline: 1.2227x; 1.2227x over previous
//
#include <hip/hip_runtime.h>
#include <stdint.h>

// ---- types ----
typedef unsigned short u16;
typedef __attribute__((ext_vector_type(4))) float f32x4;
typedef __attribute__((ext_vector_type(8))) __bf16 bf16x8;
typedef __attribute__((ext_vector_type(4))) unsigned int u32x4;

#define HWPX 4096   // H*W pixels
#define NMEM 8192   // T*H*W memory slots
#define CKD  64
#define VROWS 1024  // NOBJ*CV

__device__ __forceinline__ u16 f2bf(float x) {
    union { float f; unsigned u; } v; v.f = x;
    unsigned r = v.u + 0x7FFFu + ((v.u >> 16) & 1u);
    return (u16)(r >> 16);
}

// async global->LDS, 16B per lane; lds base wave-uniform (HW adds lane*16)
__device__ __forceinline__ void gld_lds16(const void* g, void* l) {
    __builtin_amdgcn_global_load_lds(
        (const __attribute__((address_space(1))) uint32_t*)g,
        (__attribute__((address_space(3))) uint32_t*)l, 16, 0, 0);
}

// -------- k1: tiny prep for gemm1's inputs only: Qhat/bsq (16) | Khat (32) ----
__global__ void prep_qk(const float* __restrict__ qk, const float* __restrict__ qe,
                        const float* __restrict__ mk,
                        u16* __restrict__ Qhat, float* __restrict__ bsq,
                        u16* __restrict__ Khat) {
    const int bx = blockIdx.x;
    const int tid = threadIdx.x;
    if (bx < 16) {
        int p = bx * 256 + tid;   // 4096
        float acc = 0.f;
        #pragma unroll 4
        for (int c = 0; c < CKD; ++c) {
            float k = qk[c * HWPX + p];
            float e = qe[c * HWPX + p];
            Qhat[p * 128 + c]      = f2bf(k * e);
            Qhat[p * 128 + 64 + c] = f2bf(e);
            acc += e * k * k;
        }
        bsq[p] = acc;
    } else {
        int n = (bx - 16) * 256 + tid;   // 8192
        #pragma unroll 4
        for (int c = 0; c < CKD; ++c) {
            float m = mk[c * NMEM + n];
            Khat[n * 128 + c]      = f2bf(2.f * m);
            Khat[n * 128 + 64 + c] = f2bf(-m * m);
        }
    }
}

// ---- k2 REWRITE: gemm1 tiles now 128p x 128n (2048 blocks, 4 waves of 64x64)
// r2 diagnosis: gemm1_combo ~100us (half the total budget) with worst-in-file
// structure: 4096 tiny tiles, 32x64 wave-tiles (0.047 LDS-read B/FLOP), 7
// barriers per 2.1 MFLOP. New: 128x128 tiles halve tile count, double per-wave
// reuse (0.031 B/FLOP), stage 0.023->0.015 B/FLOP. Pt layout/dpart semantics
// byte-identical to what gemm2 consumes. LDS 34.8KB -> 4 blocks/CU.
// Aux blocks (mv->bf16 convert, out zero) unchanged.
__launch_bounds__(256, 4)
__global__ void gemm1_combo(const u16* __restrict__ Qhat, const u16* __restrict__ Khat,
                            const float* __restrict__ bsq, const float* __restrict__ ms,
                            const float* __restrict__ mv,
                            u16* __restrict__ Pt, float* __restrict__ dpart,
                            u16* __restrict__ mvb, float* __restrict__ outz) {
    const int blk = blockIdx.x;
    const int tid = threadIdx.x;

    if (blk < 512) {               // mv -> bf16 (2M float4s, 4096 per block)
        #pragma unroll 4
        for (int it = 0; it < 16; ++it) {
            int i = blk * 4096 + it * 256 + tid;
            float4 v = ((const float4*)mv)[i];
            u16 o0 = f2bf(v.x), o1 = f2bf(v.y), o2 = f2bf(v.z), o3 = f2bf(v.w);
            unsigned lo = (unsigned)o0 | ((unsigned)o1 << 16);
            unsigned hi = (unsigned)o2 | ((unsigned)o3 << 16);
            ((uint2*)mvb)[i] = make_uint2(lo, hi);
        }
        return;
    }
    if (blk < 768) {               // zero out (1M float4s, 4096 per block)
        #pragma unroll 4
        for (int it = 0; it < 16; ++it) {
            int i = (blk - 512) * 4096 + it * 256 + tid;
            ((float4*)outz)[i] = make_float4(0.f, 0.f, 0.f, 0.f);
        }
        return;
    }

    // ---------------- gemm1 tile: 128 p-rows x 128 n-cols ----------------
    __shared__ __align__(16) u16 smem[17408];   // 34.8 KB (Ps [128][136])
    u16* Qs = smem;                 // [128][64] per pass (16 KB)
    u16* Ks = smem + 8192;          // [128][64] per pass (16 KB)

    const int tile = blk - 768;     // 0..2047
    const int pb = tile & 31;       // p-tile (128 wide)
    const int nb = tile >> 5;       // n-tile (128 wide), 0..63
    const int p0 = pb * 128;
    const int n0 = nb * 128;

    const int l    = tid & 63;
    const int w    = tid >> 6;
    const int quad = l >> 4;
    const int l15  = l & 15;
    const int wm = w >> 1, wn = w & 1;   // wave tile: 64p x 64n

    const int rsub = tid >> 3;                      // 0..31 (row within round)
    const int csw  = (tid & 7) ^ (rsub & 7);        // swizzled source chunk

    f32x4 acc[4][4] = {};

    #pragma unroll
    for (int h = 0; h < 2; ++h) {
        if (h) __syncthreads();     // protect stage region from pass-0 readers
        #pragma unroll
        for (int rnd = 0; rnd < 4; ++rnd)   // Q: 128 rows
            gld_lds16(Qhat + (size_t)(p0 + rnd * 32 + rsub) * 128 + h * 64 + csw * 8,
                      Qs + rnd * 2048 + w * 512);
        #pragma unroll
        for (int rnd = 0; rnd < 4; ++rnd)   // K: 128 rows
            gld_lds16(Khat + (size_t)(n0 + rnd * 32 + rsub) * 128 + h * 64 + csw * 8,
                      Ks + rnd * 2048 + w * 512);
        __syncthreads();
        #pragma unroll
        for (int kk = 0; kk < 2; ++kk) {
            bf16x8 a[4], b[4];
            #pragma unroll
            for (int mi = 0; mi < 4; ++mi) {
                int row = wm * 64 + mi * 16 + l15;
                a[mi] = *(const bf16x8*)(Qs + row * 64 + (((kk * 4 + quad) ^ (l15 & 7)) << 3));
            }
            #pragma unroll
            for (int ni = 0; ni < 4; ++ni) {
                int row = wn * 64 + ni * 16 + l15;
                b[ni] = *(const bf16x8*)(Ks + row * 64 + (((kk * 4 + quad) ^ (l15 & 7)) << 3));
            }
            #pragma unroll
            for (int mi = 0; mi < 4; ++mi)
                #pragma unroll
                for (int ni = 0; ni < 4; ++ni)
                    acc[mi][ni] = __builtin_amdgcn_mfma_f32_16x16x32_bf16(a[mi], b[ni], acc[mi][ni], 0, 0, 0);
        }
    }

    // per-lane epilogue constants
    float msv[4];
    #pragma unroll
    for (int ni = 0; ni < 4; ++ni)
        msv[ni] = ms[n0 + wn * 64 + ni * 16 + l15] * 0.125f;
    float bsv[4][4];
    #pragma unroll
    for (int mi = 0; mi < 4; ++mi)
        #pragma unroll
        for (int r = 0; r < 4; ++r)
            bsv[mi][r] = bsq[p0 + wm * 64 + mi * 16 + quad * 4 + r];

    __syncthreads();             // all waves done with stage region
    u16* Ps = smem;              // [128][136] padded u16 (34.8 KB)
    float rowsum[4][4] = {};
    #pragma unroll
    for (int mi = 0; mi < 4; ++mi) {
        #pragma unroll
        for (int ni = 0; ni < 4; ++ni) {
            f32x4 v = acc[mi][ni];
            int col = wn * 64 + ni * 16 + l15;
            #pragma unroll
            for (int r = 0; r < 4; ++r) {
                int rowl = wm * 64 + mi * 16 + quad * 4 + r;
                float pv = __expf((v[r] - bsv[mi][r]) * msv[ni]);
                rowsum[mi][r] += pv;
                Ps[rowl * 136 + col] = f2bf(pv);
            }
        }
    }
    // butterfly full-reduce over the 16-lane l15 group (16 sums/wave)
    #pragma unroll
    for (int mi = 0; mi < 4; ++mi)
        #pragma unroll
        for (int r = 0; r < 4; ++r) {
            float s = rowsum[mi][r];
            s += __shfl_xor(s, 1);
            s += __shfl_xor(s, 2);
            s += __shfl_xor(s, 4);
            s += __shfl_xor(s, 8);
            rowsum[mi][r] = s;
        }
    // exclusive-slot store: lane l15 owns (mi,r) = (l15>>2, l15&3); all 64 lanes
    {
        float myv = 0.f;
        #pragma unroll
        for (int mi = 0; mi < 4; ++mi)
            #pragma unroll
            for (int r = 0; r < 4; ++r)
                if (l15 == mi * 4 + r) myv = rowsum[mi][r];
        int slice = nb * 2 + wn;   // 0..127 (64-n spans, same semantics as before)
        dpart[(size_t)slice * HWPX + p0 + wm * 64 + (l15 >> 2) * 16 + quad * 4 + (l15 & 3)] = myv;
    }
    __syncthreads();

    // Pt store: this block owns the full 32 KB tile [pb][nb] ([128p][128n] bf16)
    {
        const size_t dstBase = ((size_t)pb * 64 + nb) * 16384;
        #pragma unroll
        for (int i = 0; i < 8; ++i) {
            int row = i * 16 + (tid >> 4);
            const u32x4* src = (const u32x4*)(Ps + row * 136 + (tid & 15) * 8);
            u32x4* dst = (u32x4*)(Pt + dstBase + row * 128 + (tid & 15) * 8);
            *dst = *src;
        }
    }
}

// ---------------- GEMM2: out += (mvb(1024x8192) * Pt_tiled^T) / denom ----
// REVERTED to the proven r0 version (101.6us). r1 deep-pipeline and r2
// A-direct-to-reg variants both failed to beat it (r2's scattered per-lane
// frag loads are TA-bound: 16 cache lines per instruction).
// Split-K=4: 1024 blocks = 4 blocks/CU. XCD swizzle: linear id bits
// [2:0]=p_lo [5:3]=v [7:6]=p_hi [9:8]=kz -> the 8 v-blocks sharing a Pt slab
// are 8 ids apart -> same XCD L2. denom reconstructed from dpart (128 slices)
// in a post-K-loop prologue; divide folded into the atomic epilogue.
__launch_bounds__(256, 4)
__global__ void gemm2_kernel(const u16* __restrict__ Ab, const u16* __restrict__ Bt,
                             const float* __restrict__ dpart, float* __restrict__ outacc) {
    __shared__ __align__(16) u16 As[128 * 64];
    __shared__ __align__(16) u16 Bs[128 * 64];

    const int tid  = threadIdx.x;
    const int l    = tid & 63;
    const int w    = tid >> 6;
    const int quad = l >> 4;
    const int l15  = l & 15;
    const int wm = w >> 1, wn = w & 1;

    const int lin = blockIdx.x + (blockIdx.y << 3) + (blockIdx.z << 8);
    const int vb  = (lin >> 3) & 7;
    const int pb  = (lin & 7) | (((lin >> 6) & 3) << 3);
    const int kz  = lin >> 8;
    const int v0 = vb * 128;
    const int p0 = pb * 128;
    const int kbeg = kz * (NMEM / 4);
    const int kend = kbeg + (NMEM / 4);

    const int rsub = tid >> 3;                      // 0..31
    const int csw  = (tid & 7) ^ (rsub & 7);        // swizzled source chunk

    f32x4 acc[4][4] = {};

    for (int k0 = kbeg; k0 < kend; k0 += 64) {
        const int nb = k0 >> 7;
        const int nh = (k0 >> 6) & 1;
        const u16* bsrc = Bt + ((size_t)pb * 64 + nb) * 16384 + nh * 64;
        __syncthreads();
        #pragma unroll
        for (int rnd = 0; rnd < 4; ++rnd) {
            gld_lds16(Ab + (size_t)(v0 + rnd * 32 + rsub) * NMEM + k0 + csw * 8,
                      As + rnd * 2048 + w * 512);
            gld_lds16(bsrc + (rnd * 32 + rsub) * 128 + csw * 8,
                      Bs + rnd * 2048 + w * 512);
        }
        __syncthreads();
        #pragma unroll
        for (int kk = 0; kk < 2; ++kk) {
            bf16x8 a[4], b[4];
            #pragma unroll
            for (int mi = 0; mi < 4; ++mi) {
                int row = wm * 64 + mi * 16 + l15;
                a[mi] = *(const bf16x8*)(As + row * 64 + (((kk * 4 + quad) ^ (l15 & 7)) << 3));
            }
            #pragma unroll
            for (int ni = 0; ni < 4; ++ni) {
                int row = wn * 64 + ni * 16 + l15;
                b[ni] = *(const bf16x8*)(Bs + row * 64 + (((kk * 4 + quad) ^ (l15 & 7)) << 3));
            }
            #pragma unroll
            for (int mi = 0; mi < 4; ++mi)
                #pragma unroll
                for (int ni = 0; ni < 4; ++ni)
                    acc[mi][ni] = __builtin_amdgcn_mfma_f32_16x16x32_bf16(a[mi], b[ni], acc[mi][ni], 0, 0, 0);
        }
    }

    // reconstruct 1/denom for this p-tile from the 128 dpart slices
    __syncthreads();                       // done reading As/Bs
    float* dtmp = (float*)As;              // 256 partials
    float* dinvs = (float*)Bs;             // 128 inverses
    {
        int p = tid & 127, h = tid >> 7;   // h: slice half
        float s = 0.f;
        #pragma unroll 8
        for (int sl = 0; sl < 64; ++sl)
            s += dpart[(size_t)(h * 64 + sl) * HWPX + p0 + p];
        dtmp[tid] = s;
    }
    __syncthreads();
    if (tid < 128) dinvs[tid] = 1.0f / (dtmp[tid] + dtmp[tid + 128]);
    __syncthreads();

    float dinv[4];
    #pragma unroll
    for (int ni = 0; ni < 4; ++ni)
        dinv[ni] = dinvs[wn * 64 + ni * 16 + l15];

    #pragma unroll
    for (int mi = 0; mi < 4; ++mi) {
        #pragma unroll
        for (int ni = 0; ni < 4; ++ni) {
            int col = p0 + wn * 64 + ni * 16 + l15;
            f32x4 v = acc[mi][ni];
            #pragma unroll
            for (int r = 0; r < 4; ++r) {
                int row = v0 + wm * 64 + mi * 16 + quad * 4 + r;
                atomicAdd(&outacc[(size_t)row * HWPX + col], v[r] * dinv[ni]);
            }
        }
    }
}

// ---------------- launch ----------------
extern "C" void kernel_launch(void* const* d_in, const int* in_sizes, int n_in,
                              void* d_out, int out_size, void* d_ws, size_t ws_size,
                              hipStream_t stream) {
    const float* qk = (const float*)d_in[0];  // (1,64,64,64)
    const float* qe = (const float*)d_in[1];  // (1,64,64,64)
    const float* mk = (const float*)d_in[2];  // (1,64,2,64,64)
    const float* ms = (const float*)d_in[3];  // (1,1,2,64,64)
    const float* mv = (const float*)d_in[4];  // (1,2,512,2,64,64)
    float* out = (float*)d_out;               // (1,2,512,64,64)

    char* ws = (char*)d_ws;
    u16*   Pt    = (u16*)ws;                               // 64 MB  tiled [32][64][128][128] bf16
    u16*   mvb   = (u16*)(ws + ((size_t)64 << 20));        // 16 MB  [1024][8192] bf16
    u16*   Khat  = (u16*)(ws + ((size_t)80 << 20));        // 2 MB   [8192][128]  bf16
    u16*   Qhat  = (u16*)(ws + ((size_t)82 << 20));        // 1 MB   [4096][128]  bf16
    float* bsq   = (float*)(ws + ((size_t)83 << 20));      // 16 KB
    float* dpart = (float*)(ws + ((size_t)83 << 20) + 65536); // 2 MB [128][4096] f32

    prep_qk<<<48, 256, 0, stream>>>(qk, qe, mk, Qhat, bsq, Khat);

    // 512 mv-convert + 256 out-zero + 2048 gemm1 tiles (128p x 128n)
    gemm1_combo<<<2816, 256, 0, stream>>>(Qhat, Khat, bsq, ms, mv, Pt, dpart, mvb, out);

    dim3 g2(8, 32, 4);  // 1024 blocks, swizzled decode inside
    gemm2_kernel<<<g2, 256, 0, stream>>>(mvb, Pt, dpart, out);
}

// Round 4
// 221.992 us; speedup vs baseline: 1.2463x; 1.0193x over previous
//
#include <hip/hip_runtime.h>
#include <stdint.h>

// ---- types ----
typedef unsigned short u16;
typedef __attribute__((ext_vector_type(4))) float f32x4;
typedef __attribute__((ext_vector_type(8))) __bf16 bf16x8;
typedef __attribute__((ext_vector_type(4))) unsigned int u32x4;

#define HWPX 4096   // H*W pixels
#define NMEM 8192   // T*H*W memory slots
#define CKD  64
#define VROWS 1024  // NOBJ*CV

__device__ __forceinline__ u16 f2bf(float x) {
    union { float f; unsigned u; } v; v.f = x;
    unsigned r = v.u + 0x7FFFu + ((v.u >> 16) & 1u);
    return (u16)(r >> 16);
}

// async global->LDS, 16B per lane; lds base wave-uniform (HW adds lane*16)
__device__ __forceinline__ void gld_lds16(const void* g, void* l) {
    __builtin_amdgcn_global_load_lds(
        (const __attribute__((address_space(1))) uint32_t*)g,
        (__attribute__((address_space(3))) uint32_t*)l, 16, 0, 0);
}

// ============================================================================
// FRAGMENT-ORDER LAYOUTS (r4). One 16B chunk = the 8 bf16 one lane feeds a
// 16x16x32 MFMA. chunk(lane l): row = base + (l&15), k = kk*32 + (l>>4)*8 + j.
// A wave's fragment load = uniform_base + l*16B -> coalesced 1KB, no LDS.
//   Qf[pt 32][h 2][wm 2][mi 4][kk 2][l 64][8]   (1 MB)  rows=p, k=ck half h
//   Kf[nt 64][h 2][wn 2][ni 4][kk 2][l 64][8]   (2 MB)  rows=n, k=ck half h
//   Ptf[pb 32][kt 128][wn 2][ni 4][kk 2][l 64][8] (64 MB) rows=p, k=n
// chunk strides (u16): l=8, kk=512, ni/mi=1024, wn/wm=4096, h=8192 (Qf/Kf),
// kt=8192 (Ptf), pt=16384, nt=16384, pb=1048576.
// ============================================================================

// -------- k1: prep -> frag-order Qf/bsq (16 blocks) | Kf (32 blocks) --------
__global__ void prep_qk(const float* __restrict__ qk, const float* __restrict__ qe,
                        const float* __restrict__ mk,
                        u16* __restrict__ Qf, float* __restrict__ bsq,
                        u16* __restrict__ Kf) {
    const int bx = blockIdx.x;
    const int tid = threadIdx.x;
    if (bx < 16) {
        int p = bx * 256 + tid;   // 4096
        const int pt = p >> 7, wm = (p >> 6) & 1, mi = (p >> 4) & 3, l15 = p & 15;
        // chunk index base (units of 512 u16), h=0, kk added later; h=1 -> +16
        const size_t cb = ((((size_t)pt * 2 + 0) * 2 + wm) * 4 + mi) * 2;
        float acc = 0.f;
        #pragma unroll
        for (int cg = 0; cg < 8; ++cg) {
            const int kk = cg >> 2, quad = cg & 3;
            float kv[8], ev[8];
            #pragma unroll
            for (int j = 0; j < 8; ++j) {
                int c = cg * 8 + j;
                kv[j] = qk[c * HWPX + p];
                ev[j] = qe[c * HWPX + p];
                acc += ev[j] * kv[j] * kv[j];
            }
            unsigned w0[4], w1[4];
            #pragma unroll
            for (int jj = 0; jj < 4; ++jj) {
                w0[jj] = (unsigned)f2bf(kv[2*jj] * ev[2*jj]) |
                         ((unsigned)f2bf(kv[2*jj+1] * ev[2*jj+1]) << 16);
                w1[jj] = (unsigned)f2bf(ev[2*jj]) |
                         ((unsigned)f2bf(ev[2*jj+1]) << 16);
            }
            const size_t off = (size_t)quad * 128 + (size_t)l15 * 8;   // l*8
            *(u32x4*)(Qf + (cb + kk) * 512 + off)      = (u32x4){w0[0], w0[1], w0[2], w0[3]};
            *(u32x4*)(Qf + (cb + 16 + kk) * 512 + off) = (u32x4){w1[0], w1[1], w1[2], w1[3]};
        }
        bsq[p] = acc;
    } else {
        int n = (bx - 16) * 256 + tid;   // 8192
        const int nt = n >> 7, wn = (n >> 6) & 1, ni = (n >> 4) & 3, l15 = n & 15;
        const size_t cb = ((((size_t)nt * 2 + 0) * 2 + wn) * 4 + ni) * 2;
        #pragma unroll
        for (int cg = 0; cg < 8; ++cg) {
            const int kk = cg >> 2, quad = cg & 3;
            float m[8];
            #pragma unroll
            for (int j = 0; j < 8; ++j)
                m[j] = mk[(cg * 8 + j) * NMEM + n];
            unsigned w0[4], w1[4];
            #pragma unroll
            for (int jj = 0; jj < 4; ++jj) {
                w0[jj] = (unsigned)f2bf(2.f * m[2*jj]) |
                         ((unsigned)f2bf(2.f * m[2*jj+1]) << 16);
                w1[jj] = (unsigned)f2bf(-m[2*jj] * m[2*jj]) |
                         ((unsigned)f2bf(-m[2*jj+1] * m[2*jj+1]) << 16);
            }
            const size_t off = (size_t)quad * 128 + (size_t)l15 * 8;
            *(u32x4*)(Kf + (cb + kk) * 512 + off)      = (u32x4){w0[0], w0[1], w0[2], w0[3]};
            *(u32x4*)(Kf + (cb + 16 + kk) * 512 + off) = (u32x4){w1[0], w1[1], w1[2], w1[3]};
        }
    }
}

// ---- k2: gemm1 tiles 128p x 128n, DIRECT-REG operands (no LDS staging, no
// main-loop barriers). Both Qf and Kf fragments arrive as coalesced 1KB
// global loads (L2/L3-resident, 3MB total). LDS used only for the Ps
// epilogue transpose. Pt written in fragment order for gemm2's direct reads.
// Aux blocks (mv->bf16 convert, out zero) unchanged.
__launch_bounds__(256, 2)
__global__ void gemm1_combo(const u16* __restrict__ Qf, const u16* __restrict__ Kf,
                            const float* __restrict__ bsq, const float* __restrict__ ms,
                            const float* __restrict__ mv,
                            u16* __restrict__ Pt, float* __restrict__ dpart,
                            u16* __restrict__ mvb, float* __restrict__ outz) {
    const int blk = blockIdx.x;
    const int tid = threadIdx.x;

    if (blk < 512) {               // mv -> bf16 (2M float4s, 4096 per block)
        #pragma unroll 4
        for (int it = 0; it < 16; ++it) {
            int i = blk * 4096 + it * 256 + tid;
            float4 v = ((const float4*)mv)[i];
            u16 o0 = f2bf(v.x), o1 = f2bf(v.y), o2 = f2bf(v.z), o3 = f2bf(v.w);
            unsigned lo = (unsigned)o0 | ((unsigned)o1 << 16);
            unsigned hi = (unsigned)o2 | ((unsigned)o3 << 16);
            ((uint2*)mvb)[i] = make_uint2(lo, hi);
        }
        return;
    }
    if (blk < 768) {               // zero out (1M float4s, 4096 per block)
        #pragma unroll 4
        for (int it = 0; it < 16; ++it) {
            int i = (blk - 512) * 4096 + it * 256 + tid;
            ((float4*)outz)[i] = make_float4(0.f, 0.f, 0.f, 0.f);
        }
        return;
    }

    // ---------------- gemm1 tile: 128 p-rows x 128 n-cols ----------------
    __shared__ __align__(16) u16 smem[17408];   // Ps [128][136] only

    const int tile = blk - 768;     // 0..2047
    const int pb = tile & 31;       // p-tile (128 wide)
    const int nb = tile >> 5;       // n-tile (128 wide), 0..63
    const int p0 = pb * 128;
    const int n0 = nb * 128;

    const int l    = tid & 63;
    const int w    = tid >> 6;
    const int quad = l >> 4;
    const int l15  = l & 15;
    const int wm = w >> 1, wn = w & 1;   // wave tile: 64p x 64n

    f32x4 acc[4][4] = {};

    #pragma unroll
    for (int h = 0; h < 2; ++h) {
        bf16x8 a[4][2], b[4][2];
        const u16* qbase = Qf + ((((size_t)pb * 2 + h) * 2 + wm) * 4096) + (size_t)l * 8;
        const u16* kbase = Kf + ((((size_t)nb * 2 + h) * 2 + wn) * 4096) + (size_t)l * 8;
        #pragma unroll
        for (int mi = 0; mi < 4; ++mi) {
            a[mi][0] = *(const bf16x8*)(qbase + mi * 1024);
            a[mi][1] = *(const bf16x8*)(qbase + mi * 1024 + 512);
        }
        #pragma unroll
        for (int ni = 0; ni < 4; ++ni) {
            b[ni][0] = *(const bf16x8*)(kbase + ni * 1024);
            b[ni][1] = *(const bf16x8*)(kbase + ni * 1024 + 512);
        }
        #pragma unroll
        for (int kk = 0; kk < 2; ++kk)
            #pragma unroll
            for (int mi = 0; mi < 4; ++mi)
                #pragma unroll
                for (int ni = 0; ni < 4; ++ni)
                    acc[mi][ni] = __builtin_amdgcn_mfma_f32_16x16x32_bf16(a[mi][kk], b[ni][kk], acc[mi][ni], 0, 0, 0);
    }

    // per-lane epilogue constants
    float msv[4];
    #pragma unroll
    for (int ni = 0; ni < 4; ++ni)
        msv[ni] = ms[n0 + wn * 64 + ni * 16 + l15] * 0.125f;
    float bsv[4][4];
    #pragma unroll
    for (int mi = 0; mi < 4; ++mi)
        #pragma unroll
        for (int r = 0; r < 4; ++r)
            bsv[mi][r] = bsq[p0 + wm * 64 + mi * 16 + quad * 4 + r];

    u16* Ps = smem;              // [128][136] padded u16
    float rowsum[4][4] = {};
    #pragma unroll
    for (int mi = 0; mi < 4; ++mi) {
        #pragma unroll
        for (int ni = 0; ni < 4; ++ni) {
            f32x4 v = acc[mi][ni];
            int col = wn * 64 + ni * 16 + l15;
            #pragma unroll
            for (int r = 0; r < 4; ++r) {
                int rowl = wm * 64 + mi * 16 + quad * 4 + r;
                float pv = __expf((v[r] - bsv[mi][r]) * msv[ni]);
                rowsum[mi][r] += pv;
                Ps[rowl * 136 + col] = f2bf(pv);
            }
        }
    }
    // butterfly full-reduce over the 16-lane l15 group (16 sums/wave)
    #pragma unroll
    for (int mi = 0; mi < 4; ++mi)
        #pragma unroll
        for (int r = 0; r < 4; ++r) {
            float s = rowsum[mi][r];
            s += __shfl_xor(s, 1);
            s += __shfl_xor(s, 2);
            s += __shfl_xor(s, 4);
            s += __shfl_xor(s, 8);
            rowsum[mi][r] = s;
        }
    // exclusive-slot store: lane l15 owns (mi,r) = (l15>>2, l15&3); all 64 lanes
    {
        float myv = 0.f;
        #pragma unroll
        for (int mi = 0; mi < 4; ++mi)
            #pragma unroll
            for (int r = 0; r < 4; ++r)
                if (l15 == mi * 4 + r) myv = rowsum[mi][r];
        int slice = nb * 2 + wn;   // 0..127 (64-n spans, same semantics as before)
        dpart[(size_t)slice * HWPX + p0 + wm * 64 + (l15 >> 2) * 16 + quad * 4 + (l15 & 3)] = myv;
    }
    __syncthreads();

    // Pt store in FRAGMENT ORDER: 32 chunks-of-1KB per block, wave-coalesced
    {
        const size_t dstBase = (size_t)pb * 1048576 + (size_t)nb * 16384;
        #pragma unroll
        for (int it = 0; it < 8; ++it) {
            const int combo = it * 4 + w;              // 0..31
            const int kt  = combo >> 4;                // local k-tile (64 n)
            const int wnq = (combo >> 3) & 1;
            const int niq = (combo >> 1) & 3;
            const int kkq = combo & 1;
            const u32x4* src = (const u32x4*)(Ps + (wnq * 64 + niq * 16 + l15) * 136
                                                 + kt * 64 + kkq * 32 + quad * 8);
            u32x4* dst = (u32x4*)(Pt + dstBase + kt * 8192 + wnq * 4096
                                     + niq * 1024 + kkq * 512 + l * 8);
            *dst = *src;
        }
    }
}

// ---------------- GEMM2 v4: A via LDS (r0-proven path), B direct-to-reg ----
// B (Ptf) fragments are coalesced 1KB global loads (L2/L3 stream) -> LDS
// traffic per block-K-tile halves (96KB -> 48KB), which r0-r3 showed is the
// binding resource. Grid/swizzle/epilogue identical to the proven r0 kernel.
__launch_bounds__(256, 3)
__global__ void gemm2_kernel(const u16* __restrict__ Ab, const u16* __restrict__ Btf,
                             const float* __restrict__ dpart, float* __restrict__ outacc) {
    __shared__ __align__(16) u16 As[128 * 64];   // 16 KB

    const int tid  = threadIdx.x;
    const int l    = tid & 63;
    const int w    = tid >> 6;
    const int quad = l >> 4;
    const int l15  = l & 15;
    const int wm = w >> 1, wn = w & 1;

    const int lin = blockIdx.x + (blockIdx.y << 3) + (blockIdx.z << 8);
    const int vb  = (lin >> 3) & 7;
    const int pb  = (lin & 7) | (((lin >> 6) & 3) << 3);
    const int kz  = lin >> 8;
    const int v0 = vb * 128;
    const int p0 = pb * 128;
    const int kbeg = kz * (NMEM / 4);
    const int kend = kbeg + (NMEM / 4);

    const int rsub = tid >> 3;                      // 0..31
    const int csw  = (tid & 7) ^ (rsub & 7);        // swizzled source chunk

    const u16* bbase = Btf + (size_t)pb * 1048576 + (size_t)wn * 4096 + (size_t)l * 8;

    f32x4 acc[4][4] = {};

    for (int k0 = kbeg; k0 < kend; k0 += 64) {
        const int kt = k0 >> 6;
        __syncthreads();
        #pragma unroll
        for (int rnd = 0; rnd < 4; ++rnd)
            gld_lds16(Ab + (size_t)(v0 + rnd * 32 + rsub) * NMEM + k0 + csw * 8,
                      As + rnd * 2048 + w * 512);
        bf16x8 b[4][2];
        {
            const u16* bk = bbase + (size_t)kt * 8192;
            #pragma unroll
            for (int ni = 0; ni < 4; ++ni) {
                b[ni][0] = *(const bf16x8*)(bk + ni * 1024);
                b[ni][1] = *(const bf16x8*)(bk + ni * 1024 + 512);
            }
        }
        __syncthreads();    // drains vmcnt: As staged AND b[] in regs
        #pragma unroll
        for (int kk = 0; kk < 2; ++kk) {
            bf16x8 a[4];
            #pragma unroll
            for (int mi = 0; mi < 4; ++mi) {
                int row = wm * 64 + mi * 16 + l15;
                a[mi] = *(const bf16x8*)(As + row * 64 + (((kk * 4 + quad) ^ (l15 & 7)) << 3));
            }
            #pragma unroll
            for (int mi = 0; mi < 4; ++mi)
                #pragma unroll
                for (int ni = 0; ni < 4; ++ni)
                    acc[mi][ni] = __builtin_amdgcn_mfma_f32_16x16x32_bf16(a[mi], b[ni][kk], acc[mi][ni], 0, 0, 0);
        }
    }

    // reconstruct 1/denom for this p-tile from the 128 dpart slices
    __syncthreads();                       // done reading As
    float* dtmp  = (float*)As;             // 256 partials (1 KB)
    float* dinvs = (float*)(As + 2048);    // 128 inverses (byte 4096)
    {
        int p = tid & 127, h = tid >> 7;   // h: slice half
        float s = 0.f;
        #pragma unroll 8
        for (int sl = 0; sl < 64; ++sl)
            s += dpart[(size_t)(h * 64 + sl) * HWPX + p0 + p];
        dtmp[tid] = s;
    }
    __syncthreads();
    if (tid < 128) dinvs[tid] = 1.0f / (dtmp[tid] + dtmp[tid + 128]);
    __syncthreads();

    float dinv[4];
    #pragma unroll
    for (int ni = 0; ni < 4; ++ni)
        dinv[ni] = dinvs[wn * 64 + ni * 16 + l15];

    #pragma unroll
    for (int mi = 0; mi < 4; ++mi) {
        #pragma unroll
        for (int ni = 0; ni < 4; ++ni) {
            int col = p0 + wn * 64 + ni * 16 + l15;
            f32x4 v = acc[mi][ni];
            #pragma unroll
            for (int r = 0; r < 4; ++r) {
                int row = v0 + wm * 64 + mi * 16 + quad * 4 + r;
                atomicAdd(&outacc[(size_t)row * HWPX + col], v[r] * dinv[ni]);
            }
        }
    }
}

// ---------------- launch ----------------
extern "C" void kernel_launch(void* const* d_in, const int* in_sizes, int n_in,
                              void* d_out, int out_size, void* d_ws, size_t ws_size,
                              hipStream_t stream) {
    const float* qk = (const float*)d_in[0];  // (1,64,64,64)
    const float* qe = (const float*)d_in[1];  // (1,64,64,64)
    const float* mk = (const float*)d_in[2];  // (1,64,2,64,64)
    const float* ms = (const float*)d_in[3];  // (1,1,2,64,64)
    const float* mv = (const float*)d_in[4];  // (1,2,512,2,64,64)
    float* out = (float*)d_out;               // (1,2,512,64,64)

    char* ws = (char*)d_ws;
    u16*   Pt    = (u16*)ws;                               // 64 MB  frag-order Ptf
    u16*   mvb   = (u16*)(ws + ((size_t)64 << 20));        // 16 MB  [1024][8192] bf16
    u16*   Kf    = (u16*)(ws + ((size_t)80 << 20));        // 2 MB   frag-order Kf
    u16*   Qf    = (u16*)(ws + ((size_t)82 << 20));        // 1 MB   frag-order Qf
    float* bsq   = (float*)(ws + ((size_t)83 << 20));      // 16 KB
    float* dpart = (float*)(ws + ((size_t)83 << 20) + 65536); // 2 MB [128][4096] f32

    prep_qk<<<48, 256, 0, stream>>>(qk, qe, mk, Qf, bsq, Kf);

    // 512 mv-convert + 256 out-zero + 2048 gemm1 tiles (128p x 128n)
    gemm1_combo<<<2816, 256, 0, stream>>>(Qf, Kf, bsq, ms, mv, Pt, dpart, mvb, out);

    dim3 g2(8, 32, 4);  // 1024 blocks, swizzled decode inside
    gemm2_kernel<<<g2, 256, 0, stream>>>(mvb, Pt, dpart, out);
}